// Round 4
// baseline (621.774 us; speedup 1.0000x reference)
//
#include <hip/hip_runtime.h>
#include <hip/hip_bf16.h>
#include <stdint.h>

#define BB 4
#define NN 512
#define HH 8

typedef __attribute__((ext_vector_type(4))) float f32x4;
typedef __attribute__((ext_vector_type(8))) __bf16 bf16x8;
typedef unsigned short u16;

union BV8 { bf16x8 v; u16 u[8]; };

__device__ __forceinline__ u16 f2bf(float f) {
    uint32_t u = __float_as_uint(f);
    u += 0x7FFFu + ((u >> 16) & 1u);   // round-to-nearest-even
    return (u16)(u >> 16);
}

// ---------------- diagnostic: fills fp32 output with a marker ----------------
__global__ __launch_bounds__(256) void marker_k(float* __restrict__ out,
                                                float val, int n) {
    int i = blockIdx.x * 256 + threadIdx.x;
    if (i < n) out[i] = val;
}

// ---------------- P0: We^T -> bf16, and sg[b,d] = g@Wg + bg + be + b2 ----------------
__global__ __launch_bounds__(256) void prep0(
    const float* __restrict__ We, const float* __restrict__ graph,
    const float* __restrict__ Wg, const float* __restrict__ bg,
    const float* __restrict__ be, const float* __restrict__ b2,
    u16* __restrict__ weT, float* __restrict__ sg) {
    int blk = blockIdx.x, tid = threadIdx.x;
    if (blk == 0) {
        for (int idx = tid; idx < 128 * 128; idx += 256) {
            int n = idx >> 7, k = idx & 127;
            weT[idx] = f2bf(We[k * 128 + n]);   // weT[n][k] = We[k][n]
        }
    } else {
        int b = blk - 1;
        if (tid < 128) {
            float acc = bg[tid] + be[tid] + b2[tid];
            for (int k = 0; k < 128; ++k)
                acc += graph[b * 128 + k] * Wg[k * 128 + tid];
            sg[b * 128 + tid] = acc;
        }
    }
}

// ---------------- P1: s1 = zW1+b1, s2c = zW2+sg, values, skip ----------------
__global__ __launch_bounds__(256) void prep1(
    const float* __restrict__ node, const float* __restrict__ hidden,
    const float* __restrict__ Wm, const float* __restrict__ bm,
    const float* __restrict__ Ws, const float* __restrict__ bs,
    const float* __restrict__ W1, const float* __restrict__ b1,
    const float* __restrict__ W2, const float* __restrict__ sg,
    float* __restrict__ s1, float* __restrict__ s2c,
    float* __restrict__ sv, float* __restrict__ ss) {
    __shared__ float zsh[8 * 256];
    int blk = blockIdx.x;            // 256 blocks: 64 per batch, 8 rows each
    int b = blk >> 6;
    int n0 = (blk & 63) << 3;
    int tid = threadIdx.x;
    for (int idx = tid; idx < 8 * 256; idx += 256) {
        int row = idx >> 8, k = idx & 255;
        size_t g = (size_t)(b * NN + n0 + row) * 128;
        zsh[idx] = (k < 128) ? node[g + k] : hidden[g + k - 128];
    }
    __syncthreads();
    int half = tid >> 7;             // 0/1 -> rows 0-3 / 4-7
    int t = tid & 127;               // output dim
    int r0 = half * 4;
    float am[4] = {0,0,0,0}, a1[4] = {0,0,0,0}, a2[4] = {0,0,0,0}, as_[4] = {0,0,0,0};
    for (int k = 0; k < 256; ++k) {
        float wm = Wm[k * 128 + t], w1 = W1[k * 128 + t];
        float w2 = W2[k * 128 + t], ws = Ws[k * 128 + t];
        #pragma unroll
        for (int r = 0; r < 4; ++r) {
            float z = zsh[(r0 + r) * 256 + k];
            am[r] += z * wm; a1[r] += z * w1; a2[r] += z * w2; as_[r] += z * ws;
        }
    }
    float sgv = sg[b * 128 + t];
    #pragma unroll
    for (int r = 0; r < 4; ++r) {
        int n = n0 + r0 + r;
        size_t rowoff = (size_t)(b * NN + n) * 128 + t;
        s1[rowoff]  = a1[r] + b1[t];
        s2c[rowoff] = a2[r] + sgv;
        ss[rowoff]  = as_[r] + bs[t];
        // values in (b,h,n,16) layout for coalesced PV reads
        sv[(size_t)((b * HH + (t >> 4)) * NN + n) * 16 + (t & 15)] = am[r] + bm[t];
    }
}

// ---------------- Fused: edge GEMM (MFMA) + logits + masked softmax + PV + skip + relu ----------------
// block = (b, i): 4 waves, wave wid owns j-strip rows [jt*128 + wid*32, +32) for jt=0..3.
__global__ __launch_bounds__(256, 2) void fused_att(
    const float* __restrict__ edge, const u16* __restrict__ weT,
    const float* __restrict__ s1, const float* __restrict__ s2c,
    const float* __restrict__ adj, const float* __restrict__ Aw,
    const float* __restrict__ Ab, const float* __restrict__ sv,
    const float* __restrict__ ss, float* __restrict__ out) {
    __shared__ u16 b_lds[128 * 128];          // 32 KB: weT[n][k], XOR-swizzled
    __shared__ float logit_lds[HH][NN];       // 16 KB: logits, then coefs
    __shared__ float mask_lds[NN];            // 2 KB
    __shared__ float red[256];                // 1 KB

    const int bid = blockIdx.x;               // b*512 + i
    const int i = bid & (NN - 1);
    const int b = bid >> 9;
    const int tid = threadIdx.x;
    const int lane = tid & 63, wid = tid >> 6;
    const int l15 = lane & 15, l4 = lane >> 4;

    // stage weT (bf16) into LDS, swizzled: 8-u16 granule at (n*128+k)^((n&7)<<3)
    for (int it = tid; it < 2048; it += 256) {
        int n = it >> 4, c = it & 15;
        int idx = (n * 128 + c * 8) ^ ((n & 7) << 3);
        *(uint4*)(&b_lds[idx]) = *(const uint4*)(weT + n * 128 + c * 8);
    }
    const float* arow = adj + (size_t)(b * NN + i) * NN;
    for (int j = tid; j < NN; j += 256) mask_lds[j] = (arow[j] - 1.0f) * 1e9f;

    // per-lane constants: s2c(i) (includes b2+be+bg), Aw, Ab
    float s2v[8], awv[8], abv[8];
    #pragma unroll
    for (int nf = 0; nf < 8; ++nf) {
        int n = nf * 16 + l15;
        s2v[nf] = s2c[(size_t)(b * NN + i) * 128 + n];
        awv[nf] = Aw[n];
        abv[nf] = Ab[nf];
    }
    __syncthreads();

    const float* s1b = s1 + (size_t)b * NN * 128;

    for (int jt = 0; jt < 4; ++jt) {
        const int jrow0 = jt * 128 + wid * 32;
        const float* eb = edge + ((size_t)(b * NN + i) * NN + jrow0) * 128;

        // A fragments from global: row jrow0+mf*16+l15, k = kk*32+l4*8 .. +7
        bf16x8 af[2][4];
        #pragma unroll
        for (int mf = 0; mf < 2; ++mf) {
            float4 raw[4][2];
            #pragma unroll
            for (int kk = 0; kk < 4; ++kk) {
                const float* p = eb + (size_t)(mf * 16 + l15) * 128 + kk * 32 + l4 * 8;
                raw[kk][0] = *(const float4*)(p);
                raw[kk][1] = *(const float4*)(p + 4);
            }
            #pragma unroll
            for (int kk = 0; kk < 4; ++kk) {
                BV8 t;
                t.u[0] = f2bf(raw[kk][0].x); t.u[1] = f2bf(raw[kk][0].y);
                t.u[2] = f2bf(raw[kk][0].z); t.u[3] = f2bf(raw[kk][0].w);
                t.u[4] = f2bf(raw[kk][1].x); t.u[5] = f2bf(raw[kk][1].y);
                t.u[6] = f2bf(raw[kk][1].z); t.u[7] = f2bf(raw[kk][1].w);
                af[mf][kk] = t.v;
            }
        }

        // acc init = s2c broadcast (C/D col value, row-independent)
        f32x4 acc[2][8];
        #pragma unroll
        for (int mf = 0; mf < 2; ++mf)
            #pragma unroll
            for (int nf = 0; nf < 8; ++nf)
                acc[mf][nf] = (f32x4){s2v[nf], s2v[nf], s2v[nf], s2v[nf]};

        #pragma unroll
        for (int kk = 0; kk < 4; ++kk)
            #pragma unroll
            for (int nf = 0; nf < 8; ++nf) {
                int bn = nf * 16 + l15;
                bf16x8 bfr = *(const bf16x8*)(
                    &b_lds[(bn * 128 + kk * 32 + l4 * 8) ^ ((bn & 7) << 3)]);
                acc[0][nf] = __builtin_amdgcn_mfma_f32_16x16x32_bf16(af[0][kk], bfr, acc[0][nf], 0, 0, 0);
                acc[1][nf] = __builtin_amdgcn_mfma_f32_16x16x32_bf16(af[1][kk], bfr, acc[1][nf], 0, 0, 0);
            }

        // epilogue: + s1[j], leaky, per-head 16-dim weighted reduce -> logit_lds
        #pragma unroll
        for (int mf = 0; mf < 2; ++mf) {
            const int rbase = jrow0 + mf * 16 + l4 * 4;
            #pragma unroll
            for (int r = 0; r < 4; ++r) {
                const float* s1r = s1b + (size_t)(rbase + r) * 128;
                #pragma unroll
                for (int nf = 0; nf < 8; ++nf) {
                    float p = acc[mf][nf][r] + s1r[nf * 16 + l15];
                    p = (p > 0.0f) ? p : 0.01f * p;
                    float tl = p * awv[nf];
                    tl += __shfl_xor(tl, 1);
                    tl += __shfl_xor(tl, 2);
                    tl += __shfl_xor(tl, 4);
                    tl += __shfl_xor(tl, 8);
                    if (l15 == 0) logit_lds[nf][rbase + r] = tl + abv[nf];
                }
            }
        }
    }
    __syncthreads();

    // masked softmax: wave wid handles heads wid*2, wid*2+1 over full j-row
    #pragma unroll
    for (int hh = 0; hh < 2; ++hh) {
        const int h = wid * 2 + hh;
        float lv[8];
        float m = -3.0e38f;
        #pragma unroll
        for (int q = 0; q < 8; ++q) {
            float l = logit_lds[h][lane + q * 64] + mask_lds[lane + q * 64];
            lv[q] = l;
            m = fmaxf(m, l);
        }
        #pragma unroll
        for (int off = 32; off; off >>= 1) m = fmaxf(m, __shfl_xor(m, off));
        float s = 0.0f;
        #pragma unroll
        for (int q = 0; q < 8; ++q) { lv[q] = __expf(lv[q] - m); s += lv[q]; }
        #pragma unroll
        for (int off = 32; off; off >>= 1) s += __shfl_xor(s, off);
        const float inv = 1.0f / s;
        #pragma unroll
        for (int q = 0; q < 8; ++q)
            logit_lds[h][lane + q * 64] = lv[q] * inv;
    }
    __syncthreads();

    // PV + skip + relu -> fp32 out
    const int d = tid & 15, ph = (tid >> 4) & 7, half = tid >> 7;
    const float* svb = sv + (size_t)(b * HH + ph) * NN * 16 + d;
    float acc2 = 0.0f;
    const int jp0 = half * 256;
    #pragma unroll 4
    for (int j = jp0; j < jp0 + 256; ++j)
        acc2 += logit_lds[ph][j] * svb[(size_t)j * 16];
    red[tid] = acc2;
    __syncthreads();
    if (tid < 128) {
        size_t o = (size_t)(b * NN + i) * 128 + tid;
        float v = red[tid] + red[tid + 128] + ss[o];
        out[o] = fmaxf(v, 0.0f);
    }
}

extern "C" void kernel_launch(void* const* d_in, const int* in_sizes, int n_in,
                              void* d_out, int out_size, void* d_ws, size_t ws_size,
                              hipStream_t stream) {
    const float* node   = (const float*)d_in[0];
    const float* edge   = (const float*)d_in[1];
    const float* graph  = (const float*)d_in[2];
    const float* adj    = (const float*)d_in[3];
    const float* hidden = (const float*)d_in[4];
    const float* Wm = (const float*)d_in[5];
    const float* bm = (const float*)d_in[6];
    const float* Ws = (const float*)d_in[7];
    const float* bs = (const float*)d_in[8];
    const float* W1 = (const float*)d_in[9];
    const float* b1 = (const float*)d_in[10];
    const float* W2 = (const float*)d_in[11];
    const float* b2 = (const float*)d_in[12];
    const float* We = (const float*)d_in[13];
    const float* be = (const float*)d_in[14];
    const float* Wg = (const float*)d_in[15];
    const float* bg = (const float*)d_in[16];
    const float* Aw = (const float*)d_in[17];
    const float* Ab = (const float*)d_in[18];

    float* outp = (float*)d_out;   // reference output dtype is float32
    const size_t WS_NEEDED = 34816 + 4u * 1048576u;   // ~4.03 MiB

    if (ws_size < WS_NEEDED) {
        // diagnostic: workspace too small -> error reads ~2000 + MiB(ws)
        marker_k<<<(out_size + 255) / 256, 256, 0, stream>>>(
            outp, 2000.0f + (float)(ws_size >> 20), out_size);
        return;
    }

    char* ws = (char*)d_ws;
    u16*   weT = (u16*)ws;                                // 32768 B
    float* sg  = (float*)(ws + 32768);                    // 2048 B
    float* s1  = (float*)(ws + 34816);                    // 1 MiB
    float* s2c = (float*)(ws + 34816 + 1048576);          // 1 MiB
    float* sv  = (float*)(ws + 34816 + 2 * 1048576);      // 1 MiB
    float* ss  = (float*)(ws + 34816 + 3 * 1048576);      // 1 MiB

    prep0<<<1 + BB, 256, 0, stream>>>(We, graph, Wg, bg, be, b2, weT, sg);
    prep1<<<256, 256, 0, stream>>>(node, hidden, Wm, bm, Ws, bs, W1, b1, W2,
                                   sg, s1, s2c, sv, ss);
    fused_att<<<BB * NN, 256, 0, stream>>>(edge, weT, s1, s2c, adj, Aw, Ab,
                                           sv, ss, outp);
}

// Round 5
// 330.848 us; speedup vs baseline: 1.8793x; 1.8793x over previous
//
#include <hip/hip_runtime.h>
#include <hip/hip_bf16.h>
#include <stdint.h>

#define BB 4
#define NN 512
#define HH 8

typedef __attribute__((ext_vector_type(4))) float f32x4;
typedef __attribute__((ext_vector_type(8))) __bf16 bf16x8;
typedef unsigned short u16;

union BV8 { bf16x8 v; u16 u[8]; };

__device__ __forceinline__ u16 f2bf(float f) {
    uint32_t u = __float_as_uint(f);
    u += 0x7FFFu + ((u >> 16) & 1u);   // round-to-nearest-even
    return (u16)(u >> 16);
}

#define GLD16(gp, lp) __builtin_amdgcn_global_load_lds( \
    (const __attribute__((address_space(1))) void*)(gp), \
    (__attribute__((address_space(3))) void*)(lp), 16, 0, 0)

// ---------------- diagnostic: fills fp32 output with a marker ----------------
__global__ __launch_bounds__(256) void marker_k(float* __restrict__ out,
                                                float val, int n) {
    int i = blockIdx.x * 256 + threadIdx.x;
    if (i < n) out[i] = val;
}

// ---------------- P0: We^T -> bf16, and sg[b,d] = g@Wg + bg + be + b2 ----------------
__global__ __launch_bounds__(256) void prep0(
    const float* __restrict__ We, const float* __restrict__ graph,
    const float* __restrict__ Wg, const float* __restrict__ bg,
    const float* __restrict__ be, const float* __restrict__ b2,
    u16* __restrict__ weT, float* __restrict__ sg) {
    int blk = blockIdx.x, tid = threadIdx.x;
    if (blk == 0) {
        for (int idx = tid; idx < 128 * 128; idx += 256) {
            int n = idx >> 7, k = idx & 127;
            weT[idx] = f2bf(We[k * 128 + n]);   // weT[n][k] = We[k][n]
        }
    } else {
        int b = blk - 1;
        if (tid < 128) {
            float acc = bg[tid] + be[tid] + b2[tid];
            for (int k = 0; k < 128; ++k)
                acc += graph[b * 128 + k] * Wg[k * 128 + tid];
            sg[b * 128 + tid] = acc;
        }
    }
}

// ---------------- P1: s1T = (zW1+b1)^T, s2c = zW2+sg, values, skip ----------------
__global__ __launch_bounds__(256) void prep1(
    const float* __restrict__ node, const float* __restrict__ hidden,
    const float* __restrict__ Wm, const float* __restrict__ bm,
    const float* __restrict__ Ws, const float* __restrict__ bs,
    const float* __restrict__ W1, const float* __restrict__ b1,
    const float* __restrict__ W2, const float* __restrict__ sg,
    float* __restrict__ s1T, float* __restrict__ s2c,
    float* __restrict__ sv, float* __restrict__ ss) {
    __shared__ float zsh[8 * 256];
    int blk = blockIdx.x;            // 256 blocks: 64 per batch, 8 rows each
    int b = blk >> 6;
    int n0 = (blk & 63) << 3;
    int tid = threadIdx.x;
    for (int idx = tid; idx < 8 * 256; idx += 256) {
        int row = idx >> 8, k = idx & 255;
        size_t g = (size_t)(b * NN + n0 + row) * 128;
        zsh[idx] = (k < 128) ? node[g + k] : hidden[g + k - 128];
    }
    __syncthreads();
    int half = tid >> 7;             // 0/1 -> rows 0-3 / 4-7
    int t = tid & 127;               // output dim
    int r0 = half * 4;
    float am[4] = {0,0,0,0}, a1[4] = {0,0,0,0}, a2[4] = {0,0,0,0}, as_[4] = {0,0,0,0};
    for (int k = 0; k < 256; ++k) {
        float wm = Wm[k * 128 + t], w1 = W1[k * 128 + t];
        float w2 = W2[k * 128 + t], ws = Ws[k * 128 + t];
        #pragma unroll
        for (int r = 0; r < 4; ++r) {
            float z = zsh[(r0 + r) * 256 + k];
            am[r] += z * wm; a1[r] += z * w1; a2[r] += z * w2; as_[r] += z * ws;
        }
    }
    float sgv = sg[b * 128 + t];
    #pragma unroll
    for (int r = 0; r < 4; ++r) {
        int n = n0 + r0 + r;         // node index j
        size_t rowoff = (size_t)(b * NN + n) * 128 + t;
        s1T[(size_t)(b * 128 + t) * NN + n] = a1[r] + b1[t];   // transposed!
        s2c[rowoff] = a2[r] + sgv;
        ss[rowoff]  = as_[r] + bs[t];
        // values in (b,h,n,16) layout for coalesced PV reads
        sv[(size_t)((b * HH + (t >> 4)) * NN + n) * 16 + (t & 15)] = am[r] + bm[t];
    }
}

// ---------------- Fused v2: gload_lds-staged edge GEMM + logits + softmax + PV ----------------
// block = (b, i); 4 waves. Wave wid owns n-cols [wid*32, +32) (heads 2wid, 2wid+1).
// j processed in 16 strips of 32 rows, double-buffered LDS staging.
__global__ __launch_bounds__(256, 3) void fused_att2(
    const float* __restrict__ edge, const u16* __restrict__ weT,
    const float* __restrict__ s1T, const float* __restrict__ s2c,
    const float* __restrict__ adj, const float* __restrict__ Aw,
    const float* __restrict__ Ab, const float* __restrict__ sv,
    const float* __restrict__ ss, float* __restrict__ out) {
    __shared__ __align__(16) float stage[2][32 * 128];   // 2 x 16 KB edge strips
    __shared__ float logit_lds[HH][NN];                  // 16 KB
    __shared__ float mask_lds[NN];                       // 2 KB
    __shared__ float red[256];                           // 1 KB

    const int bid = blockIdx.x;               // b*512 + i
    const int i = bid & (NN - 1);
    const int b = bid >> 9;
    const int tid = threadIdx.x;
    const int lane = tid & 63, wid = tid >> 6;
    const int l15 = lane & 15, l4 = lane >> 4;

    // B-fragments (We^T slice for this wave's 32 cols) -> VGPRs, from L2 (shared by all blocks)
    bf16x8 bfr[2][4];
    #pragma unroll
    for (int nf = 0; nf < 2; ++nf) {
        const int bn = wid * 32 + nf * 16 + l15;
        #pragma unroll
        for (int kk = 0; kk < 4; ++kk)
            bfr[nf][kk] = *(const bf16x8*)(weT + bn * 128 + kk * 32 + l4 * 8);
    }

    const float* arow = adj + (size_t)(b * NN + i) * NN;
    for (int j = tid; j < NN; j += 256) mask_lds[j] = (arow[j] - 1.0f) * 1e9f;

    float s2v[2], awv[2], abv[2];
    #pragma unroll
    for (int nf = 0; nf < 2; ++nf) {
        const int n = wid * 32 + nf * 16 + l15;
        s2v[nf] = s2c[(size_t)(b * NN + i) * 128 + n];
        awv[nf] = Aw[n];
        abv[nf] = Ab[(wid * 2) + nf];
    }

    const float* ebase = edge + (size_t)(b * NN + i) * NN * 128;
    const float* s1b = s1T + (size_t)b * 128 * NN;

    // ---- staging helper (macro to keep gload_lds size literal) ----
    // strip s: rows [s*32, +32), 16 KB. slot t covers row r=t>>5, dest granule gs=t&31,
    // source granule g = gs ^ (r&7)  (involution; ds_read applies same XOR)
    #define STAGE(buf, s) do {                                              \
        const float* sb = ebase + (size_t)(s) * 32 * 128;                   \
        _Pragma("unroll")                                                   \
        for (int it = 0; it < 4; ++it) {                                    \
            const int slotu = it * 256 + wid * 64;                          \
            float* ldst = &stage[buf][slotu * 4];                           \
            const int myslot = slotu + lane;                                \
            const int r = myslot >> 5, gs = myslot & 31;                    \
            const int g = gs ^ (r & 7);                                     \
            GLD16(sb + r * 128 + g * 4, ldst);                              \
        }                                                                   \
    } while (0)

    STAGE(0, 0);
    __syncthreads();   // drains vmcnt: strip 0 ready

    for (int s = 0; s < 16; ++s) {
        const int cur = s & 1;
        if (s < 15) STAGE(cur ^ 1, s + 1);      // prefetch next strip (in flight thru compute)

        const int strip0 = s * 32;
        const float* st = stage[cur];

        // A fragments from LDS (swizzled), fp32 -> bf16
        bf16x8 af[2][4];
        #pragma unroll
        for (int mf = 0; mf < 2; ++mf) {
            const int R = mf * 16 + l15;
            #pragma unroll
            for (int kk = 0; kk < 4; ++kk) {
                const int g0 = kk * 8 + l4 * 2;
                const float4 lo = *(const float4*)&st[(R * 32 + (g0 ^ (R & 7))) * 4];
                const float4 hi = *(const float4*)&st[(R * 32 + ((g0 + 1) ^ (R & 7))) * 4];
                BV8 t;
                t.u[0] = f2bf(lo.x); t.u[1] = f2bf(lo.y);
                t.u[2] = f2bf(lo.z); t.u[3] = f2bf(lo.w);
                t.u[4] = f2bf(hi.x); t.u[5] = f2bf(hi.y);
                t.u[6] = f2bf(hi.z); t.u[7] = f2bf(hi.w);
                af[mf][kk] = t.v;
            }
        }

        // s1T prefetch: contiguous float4 over j (issued before MFMA; L2)
        float4 s1v[2][2];
        #pragma unroll
        for (int mf = 0; mf < 2; ++mf)
            #pragma unroll
            for (int nf = 0; nf < 2; ++nf)
                s1v[mf][nf] = *(const float4*)(
                    s1b + (size_t)(wid * 32 + nf * 16 + l15) * NN
                        + strip0 + mf * 16 + l4 * 4);

        f32x4 acc[2][2];
        #pragma unroll
        for (int mf = 0; mf < 2; ++mf)
            #pragma unroll
            for (int nf = 0; nf < 2; ++nf)
                acc[mf][nf] = (f32x4){s2v[nf], s2v[nf], s2v[nf], s2v[nf]};

        #pragma unroll
        for (int kk = 0; kk < 4; ++kk)
            #pragma unroll
            for (int mf = 0; mf < 2; ++mf) {
                acc[mf][0] = __builtin_amdgcn_mfma_f32_16x16x32_bf16(af[mf][kk], bfr[0][kk], acc[mf][0], 0, 0, 0);
                acc[mf][1] = __builtin_amdgcn_mfma_f32_16x16x32_bf16(af[mf][kk], bfr[1][kk], acc[mf][1], 0, 0, 0);
            }

        // epilogue: + s1, leaky, *Aw, 16-lane reduce -> logit_lds
        #pragma unroll
        for (int mf = 0; mf < 2; ++mf) {
            #pragma unroll
            for (int nf = 0; nf < 2; ++nf) {
                const float s1r[4] = {s1v[mf][nf].x, s1v[mf][nf].y,
                                      s1v[mf][nf].z, s1v[mf][nf].w};
                #pragma unroll
                for (int r = 0; r < 4; ++r) {
                    float p = acc[mf][nf][r] + s1r[r];
                    p = (p > 0.0f) ? p : 0.01f * p;
                    float tl = p * awv[nf];
                    tl += __shfl_xor(tl, 1);
                    tl += __shfl_xor(tl, 2);
                    tl += __shfl_xor(tl, 4);
                    tl += __shfl_xor(tl, 8);
                    if (l15 == 0)
                        logit_lds[wid * 2 + nf][strip0 + mf * 16 + l4 * 4 + r] = tl + abv[nf];
                }
            }
        }
        __syncthreads();   // drains vmcnt (next strip ready) + logit visibility
    }

    // masked softmax: wave wid handles heads wid*2, wid*2+1 over full j-row
    #pragma unroll
    for (int hh = 0; hh < 2; ++hh) {
        const int h = wid * 2 + hh;
        float lv[8];
        float m = -3.0e38f;
        #pragma unroll
        for (int q = 0; q < 8; ++q) {
            float l = logit_lds[h][lane + q * 64] + mask_lds[lane + q * 64];
            lv[q] = l;
            m = fmaxf(m, l);
        }
        #pragma unroll
        for (int off = 32; off; off >>= 1) m = fmaxf(m, __shfl_xor(m, off));
        float s = 0.0f;
        #pragma unroll
        for (int q = 0; q < 8; ++q) { lv[q] = __expf(lv[q] - m); s += lv[q]; }
        #pragma unroll
        for (int off = 32; off; off >>= 1) s += __shfl_xor(s, off);
        const float inv = 1.0f / s;
        #pragma unroll
        for (int q = 0; q < 8; ++q)
            logit_lds[h][lane + q * 64] = lv[q] * inv;
    }
    __syncthreads();

    // PV + skip + relu -> fp32 out
    const int d = tid & 15, ph = (tid >> 4) & 7, half = tid >> 7;
    const float* svb = sv + (size_t)(b * HH + ph) * NN * 16 + d;
    float acc2 = 0.0f;
    const int jp0 = half * 256;
    #pragma unroll 4
    for (int j = jp0; j < jp0 + 256; ++j)
        acc2 += logit_lds[ph][j] * svb[(size_t)j * 16];
    red[tid] = acc2;
    __syncthreads();
    if (tid < 128) {
        size_t o = (size_t)(b * NN + i) * 128 + tid;
        float v = red[tid] + red[tid + 128] + ss[o];
        out[o] = fmaxf(v, 0.0f);
    }
    #undef STAGE
}

extern "C" void kernel_launch(void* const* d_in, const int* in_sizes, int n_in,
                              void* d_out, int out_size, void* d_ws, size_t ws_size,
                              hipStream_t stream) {
    const float* node   = (const float*)d_in[0];
    const float* edge   = (const float*)d_in[1];
    const float* graph  = (const float*)d_in[2];
    const float* adj    = (const float*)d_in[3];
    const float* hidden = (const float*)d_in[4];
    const float* Wm = (const float*)d_in[5];
    const float* bm = (const float*)d_in[6];
    const float* Ws = (const float*)d_in[7];
    const float* bs = (const float*)d_in[8];
    const float* W1 = (const float*)d_in[9];
    const float* b1 = (const float*)d_in[10];
    const float* W2 = (const float*)d_in[11];
    const float* b2 = (const float*)d_in[12];
    const float* We = (const float*)d_in[13];
    const float* be = (const float*)d_in[14];
    const float* Wg = (const float*)d_in[15];
    const float* bg = (const float*)d_in[16];
    const float* Aw = (const float*)d_in[17];
    const float* Ab = (const float*)d_in[18];

    float* outp = (float*)d_out;   // reference output dtype is float32
    const size_t WS_NEEDED = 34816 + 4u * 1048576u;   // ~4.03 MiB

    if (ws_size < WS_NEEDED) {
        marker_k<<<(out_size + 255) / 256, 256, 0, stream>>>(
            outp, 2000.0f + (float)(ws_size >> 20), out_size);
        return;
    }

    char* ws = (char*)d_ws;
    u16*   weT = (u16*)ws;                                // 32768 B
    float* sg  = (float*)(ws + 32768);                    // 2048 B
    float* s1T = (float*)(ws + 34816);                    // 1 MiB (transposed [b][n][j])
    float* s2c = (float*)(ws + 34816 + 1048576);          // 1 MiB
    float* sv  = (float*)(ws + 34816 + 2 * 1048576);      // 1 MiB
    float* ss  = (float*)(ws + 34816 + 3 * 1048576);      // 1 MiB

    prep0<<<1 + BB, 256, 0, stream>>>(We, graph, Wg, bg, be, b2, weT, sg);
    prep1<<<256, 256, 0, stream>>>(node, hidden, Wm, bm, Ws, bs, W1, b1, W2,
                                   sg, s1T, s2c, sv, ss);
    fused_att2<<<BB * NN, 256, 0, stream>>>(edge, weT, s1T, s2c, adj, Aw, Ab,
                                            sv, ss, outp);
}